// Round 24
// baseline (82.754 us; speedup 1.0000x reference)
//
#include <hip/hip_runtime.h>
#include <stdint.h>

// Problem constants
#define S_LEN 2048
#define D_DIM 1024
#define NB 2
#define NH 16
#define NE 64
#define QK_COLS 2048          // stored cols of qk buffer (Q | K)
#define K_DIM D_DIM           // 1024

typedef unsigned short u16;
typedef unsigned int u32;
typedef u16 u16x8 __attribute__((ext_vector_type(8)));
typedef __bf16 bf16x8 __attribute__((ext_vector_type(8)));
typedef float f32x4 __attribute__((ext_vector_type(4)));

__device__ __forceinline__ u16 f2b(float f) {
  u32 u = __builtin_bit_cast(u32, f);
  return (u16)((u + 0x7FFFu + ((u >> 16) & 1u)) >> 16);  // RNE
}

__device__ __forceinline__ void gload_lds16(const void* g, void* l) {
  __builtin_amdgcn_global_load_lds(
      (const __attribute__((address_space(1))) u32*)g,
      (__attribute__((address_space(3))) u32*)l, 16, 0, 0);
}

// sigma: bit-permutation on [0,64): out{b5,b4,b3,b2,b1,b0} = {b5, b3, b2, b4, b1, b0}.
// Applied to K staging so PV's register-local P k-map aligns with NATURAL V^T order.
__device__ __forceinline__ int sigma64(int m) {
  return (m & 32) | ((m & 12) << 1) | ((m & 16) >> 2) | (m & 3);
}

// ---------- merged prep: blocks [0,2048) convert x; [2048,2816) transpose W ----------
__global__ __launch_bounds__(256) void k_prep(const float* __restrict__ x,
                                              const float* __restrict__ Wq,
                                              const float* __restrict__ Wk,
                                              const float* __restrict__ Wv,
                                              u16* __restrict__ xb,
                                              u16* __restrict__ Wt) {
  __shared__ u16 tile[64][65];
  int bid = blockIdx.x;
  int t = threadIdx.x;
  if (bid < 2048) {
    size_t i = (size_t)bid * 256 + t;
    const float4* xf = (const float4*)x;
    float4 a = xf[2 * i], c = xf[2 * i + 1];
    u16x8 o;
    o[0] = f2b(a.x); o[1] = f2b(a.y); o[2] = f2b(a.z); o[3] = f2b(a.w);
    o[4] = f2b(c.x); o[5] = f2b(c.y); o[6] = f2b(c.z); o[7] = f2b(c.w);
    *(u16x8*)(xb + 8 * i) = o;
  } else {
    int wbid = bid - 2048;             // proj*256 + h*16 + kb
    int kb = wbid & 15;
    int h = (wbid >> 4) & 15;
    int proj = wbid >> 8;
    const float* W = (proj == 0) ? Wq : ((proj == 1) ? Wk : Wv);
    int k0 = kb * 64;
    int e = t & 63, kr = t >> 6;
    const float* src = W + ((size_t)h * D_DIM + k0 + kr * 16) * NE + e;
#pragma unroll
    for (int j = 0; j < 16; ++j) tile[kr * 16 + j][e] = f2b(src[(size_t)j * NE]);
    __syncthreads();
    int e2 = t >> 2, kc = (t & 3) * 16;
    u16x8 o0, o1;
#pragma unroll
    for (int j = 0; j < 8; ++j) { o0[j] = tile[kc + j][e2]; o1[j] = tile[kc + 8 + j][e2]; }
    size_t n = (size_t)proj * 1024 + h * 64 + e2;
    u16* dst = Wt + n * K_DIM + k0 + kc;
    *(u16x8*)dst = o0;
    *(u16x8*)(dst + 8) = o1;
  }
}

// ------------- GEMM (two families, interleaved; BK=32 dbuf, 32 KB LDS, 3 blocks/CU) -------------
// BK=32 double-buffer, single barrier per K-step, stage(t+1) before compute(t).
// LDS layout per operand: 64 rows x 128 B (two K-rows merged per LDS row) with the
// PROVEN 8-chunk XOR swizzle: global (r, k-chunk hi) <-> cc=(r&1)*4+hi, LDS slot
// c' = cc ^ ((r>>1)&7). Same structure as the 0-conflict BK=64 kernel (16
// consecutive lanes cover all 8 bank positions, 2 each = free). Staging inverts
// the bijection on the DMA source; dest stays linear.
// r0%3<2 (QK): Cqk[4096,2048] = xb @ Wt[0:2048]^T, qi=(r0/3)*2+(r0%3):
//   m0=(qi>>1)*128, n0=(xcd*2+(qi&1))*128. Q cols pre-scaled by 0.125*log2e.
// r0%3==2 (VT): transposed-V directly: A = Wt rows 2048+xcd*128, B = xb rows
//   (r0/3)*128; store VT[(s>>11)*1024+vrow][s&2047] coalesced.
__global__ __launch_bounds__(256) void k_gemm(const u16* __restrict__ A,
                                              const u16* __restrict__ Bt,
                                              u16* __restrict__ Cqk,
                                              u16* __restrict__ VT) {
  __shared__ __align__(16) u16 As[2][64 * 64];   // 64 rows x 64 u16 (128 B)
  __shared__ __align__(16) u16 Bs[2][64 * 64];
  int t = threadIdx.x;
  int lane = t & 63, w = t >> 6;
  int hi = lane >> 4, l15 = lane & 15;
  int wr = (w >> 1) * 64, wc = (w & 1) * 64;
  int bid = blockIdx.x;
  int xcd = bid & 7, r0 = bid >> 3;          // r0 in [0,96)
  int fam3 = r0 % 3;
  bool isV = (fam3 == 2);
  int m0, n0;
  const u16 *arows, *brows;
  if (!isV) {
    int qi = (r0 / 3) * 2 + fam3;            // [0,64)
    m0 = (qi >> 1) * 128;
    n0 = (xcd * 2 + (qi & 1)) * 128;
    arows = A + (size_t)m0 * K_DIM;
    brows = Bt + (size_t)n0 * K_DIM;
  } else {
    m0 = xcd * 128;                          // vrow panel
    n0 = (r0 / 3) * 128;                     // s panel
    arows = Bt + (size_t)(2048 + m0) * K_DIM;
    brows = A + (size_t)n0 * K_DIM;
  }
  float qscale = (!isV && (n0 + wc) < 1024) ? 0.18033688f : 1.0f;  // 0.125*log2e
  f32x4 acc[4][4];
#pragma unroll
  for (int m = 0; m < 4; m++)
#pragma unroll
    for (int n = 0; n < 4; n++)
#pragma unroll
      for (int j = 0; j < 4; j++) acc[m][n][j] = 0.f;

  auto stage = [&](int buf, int k0) {
#pragma unroll
    for (int i = 0; i < 2; ++i) {
      int ci = i * 256 + t;                  // linear 16B-chunk index [0,512)
      int rowp = ci >> 3, cp = ci & 7;       // LDS row' (0..63), chunk c'
      int cc = cp ^ (rowp & 7);              // unswizzled chunk
      int r = 2 * rowp + (cc >> 2);          // global tile row
      int kchunk = cc & 3;                   // k-chunk (8 u16)
      gload_lds16(arows + (size_t)r * K_DIM + k0 + kchunk * 8,
                  (char*)As[buf] + (size_t)(i * 256 + w * 64) * 16);
      gload_lds16(brows + (size_t)r * K_DIM + k0 + kchunk * 8,
                  (char*)Bs[buf] + (size_t)(i * 256 + w * 64) * 16);
    }
  };

  stage(0, 0);
  __syncthreads();

  int cur = 0;
  for (int t32 = 0; t32 < 32; ++t32) {
    if (t32 < 31) stage(cur ^ 1, (t32 + 1) * 32);   // loads in flight during compute
    bf16x8 af[4], bfr[4];
#pragma unroll
    for (int m = 0; m < 4; m++) {
      int r = wr + m * 16 + l15;
      int rowp = r >> 1;
      int cp = ((r & 1) * 4 + hi) ^ (rowp & 7);
      af[m] = *(const bf16x8*)&As[cur][rowp * 64 + cp * 8];
    }
#pragma unroll
    for (int n = 0; n < 4; n++) {
      int r = wc + n * 16 + l15;
      int rowp = r >> 1;
      int cp = ((r & 1) * 4 + hi) ^ (rowp & 7);
      bfr[n] = *(const bf16x8*)&Bs[cur][rowp * 64 + cp * 8];
    }
    __builtin_amdgcn_s_setprio(1);
#pragma unroll
    for (int m = 0; m < 4; m++)
#pragma unroll
      for (int n = 0; n < 4; n++)
        acc[m][n] = __builtin_amdgcn_mfma_f32_16x16x32_bf16(af[m], bfr[n], acc[m][n], 0, 0, 0);
    __builtin_amdgcn_s_setprio(0);
    __syncthreads();   // drains next-tile DMA (covered by compute) + frees cur
    cur ^= 1;
  }

  if (!isV) {
#pragma unroll
    for (int m = 0; m < 4; m++) {
#pragma unroll
      for (int r = 0; r < 4; r++) {
        int row = m0 + wr + m * 16 + hi * 4 + r;
#pragma unroll
        for (int n = 0; n < 4; n++) {
          int col = n0 + wc + n * 16 + l15;
          Cqk[(size_t)row * QK_COLS + col] = f2b(acc[m][n][r] * qscale);
        }
      }
    }
  } else {
#pragma unroll
    for (int m = 0; m < 4; m++) {
#pragma unroll
      for (int r = 0; r < 4; r++) {
        int vrow = m0 + wr + m * 16 + hi * 4 + r;      // 0..1023 (h*64+e)
#pragma unroll
        for (int n = 0; n < 4; n++) {
          int col = n0 + wc + n * 16 + l15;            // s in [0,4096)
          VT[(size_t)((col >> 11) * 1024 + vrow) * S_LEN + (col & 2047)] =
              f2b(acc[m][n][r]);
        }
      }
    }
  }
}

// ---- attention helpers (256-thread block) ----
// K staging with sigma-permuted SOURCE rows: LDS row r holds kv0+sigma(r); the
// XOR chunk swizzle keys on the LDS row (read side unchanged).
__device__ __forceinline__ void stage_k(const u16* kb_, u16* kdst, int kv0, int t, int w) {
#pragma unroll
  for (int i = 0; i < 2; ++i) {
    int ci = i * 256 + t;
    int row = ci >> 3, c = ci & 7;
    int srow = sigma64(row);
    int cs = c ^ (row & 7);
    gload_lds16(kb_ + (size_t)(kv0 + srow) * QK_COLS + cs * 8,
                (char*)kdst + (size_t)(i * 256 + w * 64) * 16);  // wave-uniform base
  }
}

// V^T stage: VT rows are e (stride S_LEN u16), tile cols [kv0, kv0+64) natural order.
__device__ __forceinline__ void stage_v(const u16* vtb_, u16* vdst, int kv0, int t, int w) {
#pragma unroll
  for (int i = 0; i < 2; ++i) {
    int ci = i * 256 + t;
    int row = ci >> 3, c = ci & 7;
    int cs = c ^ (row & 7);
    gload_lds16(vtb_ + (size_t)row * S_LEN + kv0 + cs * 8,
                (char*)vdst + (size_t)(i * 256 + w * 64) * 16);
  }
}

// ------- flash attention, causal, swapped-QK^T register-P, DMA-staged V^T -------
// 1024 blocks x 4 waves; x=bid&7, g=bid>>3, bh=x*4+(g&3) (4 heads' K/V per XCD L2),
// qt=31-(g>>2) (LPT). Wave owns 16 q rows. QK^T as mfma(K,Q) -> P register-local.
// Ks rows sigma-permuted at staging so PV's A k-map (kv=32ks+8hi+j) aligns with
// NATURAL V^T columns: V fragment = ONE b128, A/B k-maps agree exactly.
// Diagonal mask uses kv = kv0 + sigma(16f+4hi+r). No-max exp2 softmax.
__global__ __launch_bounds__(256) void k_attn(const u16* __restrict__ qk,
                                              const u16* __restrict__ VT,
                                              float* __restrict__ out) {
  __shared__ __align__(16) u16 Ks[2][64 * 64];
  __shared__ __align__(16) u16 Vs[2][64 * 64];
  int t = threadIdx.x;
  int lane = t & 63, w = t >> 6;
  int hi = lane >> 4, l15 = lane & 15;
  int bid = blockIdx.x;                 // 0..1023
  int x = bid & 7, g = bid >> 3;
  int bh = x * 4 + (g & 3);
  int qt = 31 - (g >> 2);
  int b = bh >> 4, h = bh & 15;
  const u16* qb_ = qk + (size_t)b * S_LEN * QK_COLS + h * NE;
  const u16* kb_ = qb_ + 1024;
  const u16* vtb_ = VT + (size_t)bh * 64 * S_LEN;

  int q0 = qt * 64;
  int nt = qt + 1;
  int wqb = q0 + w * 16;                // wave q base; lane q = wqb + l15

  bf16x8 qf[2];
#pragma unroll
  for (int ks = 0; ks < 2; ks++)
    qf[ks] = *(const bf16x8*)(qb_ + (size_t)(wqb + l15) * QK_COLS + ks * 32 + hi * 8);

  f32x4 o[4];
#pragma unroll
  for (int i = 0; i < 4; i++)
#pragma unroll
    for (int j = 0; j < 4; j++) o[i][j] = 0.f;
  float lsum = 0.f;
  int myq = wqb + l15;

  // prologue: stage tile 0 into buffer 0
  stage_k(kb_, Ks[0], 0, t, w);
  stage_v(vtb_, Vs[0], 0, t, w);
  __syncthreads();

  int cur = 0;
  for (int ti = 0; ti < nt; ++ti) {
    int kv0 = ti * 64;
    bool pf = (ti + 1 < nt);
    if (pf) {
      stage_k(kb_, Ks[cur ^ 1], kv0 + 64, t, w);
      stage_v(vtb_, Vs[cur ^ 1], kv0 + 64, t, w);
    }

    // S^T = K Q : s[f][r] = S[kv = kv0 + sigma(16f+4hi+r)][q = myq]
    f32x4 s[4];
#pragma unroll
    for (int f = 0; f < 4; f++)
#pragma unroll
      for (int j = 0; j < 4; j++) s[f][j] = 0.f;
    __builtin_amdgcn_s_setprio(1);
#pragma unroll
    for (int ks = 0; ks < 2; ks++) {
      int kc = ks * 4 + hi;
#pragma unroll
      for (int f = 0; f < 4; f++) {
        int r = f * 16 + l15;
        bf16x8 kf = *(const bf16x8*)&Ks[cur][r * 64 + ((kc ^ (r & 7)) * 8)];
        s[f] = __builtin_amdgcn_mfma_f32_16x16x32_bf16(kf, qf[ks], s[f], 0, 0, 0);
      }
    }
    __builtin_amdgcn_s_setprio(0);

    // no-max softmax: p = exp2(s); diagonal mask with sigma-mapped kv
    bool diag = (ti == nt - 1);
#pragma unroll
    for (int f = 0; f < 4; f++) {
#pragma unroll
      for (int r = 0; r < 4; r++) {
        float p = __builtin_amdgcn_exp2f(s[f][r]);
        if (diag) {
          int kv = kv0 + sigma64(16 * f + 4 * hi + r);
          p = (kv <= myq) ? p : 0.f;
        }
        s[f][r] = p;
        lsum += p;
      }
    }

    // PV: pa register-local (pa slot (hi,j) holds kv = 32ks+8hi+j after sigma);
    // V fragment = ONE b128 from Vs natural layout, chunk (4ks+hi)^(e&7).
    __builtin_amdgcn_s_setprio(1);
#pragma unroll
    for (int ks = 0; ks < 2; ks++) {
      bf16x8 pa;
#pragma unroll
      for (int j = 0; j < 4; j++) {
        pa[j] = (__bf16)s[2 * ks][j];
        pa[4 + j] = (__bf16)s[2 * ks + 1][j];
      }
#pragma unroll
      for (int ef = 0; ef < 4; ef++) {
        int e = ef * 16 + l15;
        bf16x8 vbf = *(const bf16x8*)&Vs[cur][e * 64 + (((4 * ks + hi) ^ (e & 7)) * 8)];
        o[ef] = __builtin_amdgcn_mfma_f32_16x16x32_bf16(pa, vbf, o[ef], 0, 0, 0);
      }
    }
    __builtin_amdgcn_s_setprio(0);
    __syncthreads();
    cur ^= 1;
  }

  // epilogue: complete row-sum across hi groups, redistribute, normalize, store.
  lsum += __shfl_xor(lsum, 16);
  lsum += __shfl_xor(lsum, 32);
#pragma unroll
  for (int r = 0; r < 4; r++) {
    float l = __shfl(lsum, 4 * hi + r);  // lane 4hi+r holds sum for q = wqb+4hi+r
    float inv = 1.0f / l;
    int q = wqb + 4 * hi + r;
#pragma unroll
    for (int ef = 0; ef < 4; ef++) {
      int col = h * NE + ef * 16 + l15;
      out[((size_t)b * S_LEN + q) * (NH * NE) + col] = o[ef][r] * inv;
    }
  }
}

extern "C" void kernel_launch(void* const* d_in, const int* in_sizes, int n_in,
                              void* d_out, int out_size, void* d_ws, size_t ws_size,
                              hipStream_t stream) {
  const float* x = (const float*)d_in[0];
  const float* Wq = (const float*)d_in[1];
  const float* Wk = (const float*)d_in[2];
  const float* Wv = (const float*)d_in[3];
  float* out = (float*)d_out;

  char* ws = (char*)d_ws;
  u16* xb = (u16*)ws;                          // 4096*1024*2  = 8 MB
  u16* Wt = (u16*)(ws + (8u << 20));           // 3072*1024*2  = 6 MB
  u16* qk = (u16*)(ws + (14u << 20));          // 4096*2048*2  = 16 MB
  u16* VT = (u16*)(ws + (30u << 20));          // 32*64*2048*2 = 8 MB

  k_prep<<<dim3(2816), dim3(256), 0, stream>>>(x, Wq, Wk, Wv, xb, Wt);
  k_gemm<<<dim3(768), dim3(256), 0, stream>>>(xb, Wt, qk, VT);
  k_attn<<<dim3(1024), dim3(256), 0, stream>>>(qk, VT, out);
}

// Round 25
// 82.622 us; speedup vs baseline: 1.0016x; 1.0016x over previous
//
#include <hip/hip_runtime.h>
#include <stdint.h>

// Problem constants
#define S_LEN 2048
#define D_DIM 1024
#define NB 2
#define NH 16
#define NE 64
#define QK_COLS 2048          // stored cols of qk buffer (Q | K)
#define K_DIM D_DIM           // 1024

typedef unsigned short u16;
typedef unsigned int u32;
typedef u16 u16x8 __attribute__((ext_vector_type(8)));
typedef __bf16 bf16x8 __attribute__((ext_vector_type(8)));
typedef float f32x4 __attribute__((ext_vector_type(4)));

__device__ __forceinline__ u16 f2b(float f) {
  u32 u = __builtin_bit_cast(u32, f);
  return (u16)((u + 0x7FFFu + ((u >> 16) & 1u)) >> 16);  // RNE
}

__device__ __forceinline__ void gload_lds16(const void* g, void* l) {
  __builtin_amdgcn_global_load_lds(
      (const __attribute__((address_space(1))) u32*)g,
      (__attribute__((address_space(3))) u32*)l, 16, 0, 0);
}

// sigma: bit-permutation on [0,64): out{b5,b4,b3,b2,b1,b0} = {b5, b3, b2, b4, b1, b0}.
// Applied to K staging so PV's register-local P k-map aligns with NATURAL V^T order.
__device__ __forceinline__ int sigma64(int m) {
  return (m & 32) | ((m & 12) << 1) | ((m & 16) >> 2) | (m & 3);
}

// ---------- merged prep: blocks [0,2048) convert x; [2048,2816) transpose W ----------
__global__ __launch_bounds__(256) void k_prep(const float* __restrict__ x,
                                              const float* __restrict__ Wq,
                                              const float* __restrict__ Wk,
                                              const float* __restrict__ Wv,
                                              u16* __restrict__ xb,
                                              u16* __restrict__ Wt) {
  __shared__ u16 tile[64][65];
  int bid = blockIdx.x;
  int t = threadIdx.x;
  if (bid < 2048) {
    size_t i = (size_t)bid * 256 + t;
    const float4* xf = (const float4*)x;
    float4 a = xf[2 * i], c = xf[2 * i + 1];
    u16x8 o;
    o[0] = f2b(a.x); o[1] = f2b(a.y); o[2] = f2b(a.z); o[3] = f2b(a.w);
    o[4] = f2b(c.x); o[5] = f2b(c.y); o[6] = f2b(c.z); o[7] = f2b(c.w);
    *(u16x8*)(xb + 8 * i) = o;
  } else {
    int wbid = bid - 2048;             // proj*256 + h*16 + kb
    int kb = wbid & 15;
    int h = (wbid >> 4) & 15;
    int proj = wbid >> 8;
    const float* W = (proj == 0) ? Wq : ((proj == 1) ? Wk : Wv);
    int k0 = kb * 64;
    int e = t & 63, kr = t >> 6;
    const float* src = W + ((size_t)h * D_DIM + k0 + kr * 16) * NE + e;
#pragma unroll
    for (int j = 0; j < 16; ++j) tile[kr * 16 + j][e] = f2b(src[(size_t)j * NE]);
    __syncthreads();
    int e2 = t >> 2, kc = (t & 3) * 16;
    u16x8 o0, o1;
#pragma unroll
    for (int j = 0; j < 8; ++j) { o0[j] = tile[kc + j][e2]; o1[j] = tile[kc + 8 + j][e2]; }
    size_t n = (size_t)proj * 1024 + h * 64 + e2;
    u16* dst = Wt + n * K_DIM + k0 + kc;
    *(u16x8*)dst = o0;
    *(u16x8*)(dst + 8) = o1;
  }
}

// ------------- GEMM (two families, interleaved; BK=32 dbuf, hoisted addressing) -------------
// BK=32 double-buffer, single barrier per K-step, stage(t+1) before compute(t).
// LDS layout: 64 rows x 128 B (two K-rows merged per LDS row), 8-chunk XOR swizzle
// c' = cc ^ ((r>>1)&7), cc=(r&1)*4+hi (0 bank conflicts, verified r24).
// ALL loop-invariant addressing hoisted (r24 showed VALUBusy 38.7% > MfmaUtil 24.3%
// from per-step address recomputation): staging source pointers advance by +=32;
// MFMA LDS read offsets precomputed per lane.
// r0%3<2 (QK): Cqk[4096,2048] = xb @ Wt[0:2048]^T, qi=(r0/3)*2+(r0%3):
//   m0=(qi>>1)*128, n0=(xcd*2+(qi&1))*128. Q cols pre-scaled by 0.125*log2e.
// r0%3==2 (VT): transposed-V directly: A = Wt rows 2048+xcd*128, B = xb rows
//   (r0/3)*128; store VT[(s>>11)*1024+vrow][s&2047] coalesced.
__global__ __launch_bounds__(256) void k_gemm(const u16* __restrict__ A,
                                              const u16* __restrict__ Bt,
                                              u16* __restrict__ Cqk,
                                              u16* __restrict__ VT) {
  __shared__ __align__(16) u16 As[2][64 * 64];   // 64 rows x 64 u16 (128 B)
  __shared__ __align__(16) u16 Bs[2][64 * 64];
  int t = threadIdx.x;
  int lane = t & 63, w = t >> 6;
  int hi = lane >> 4, l15 = lane & 15;
  int wr = (w >> 1) * 64, wc = (w & 1) * 64;
  int bid = blockIdx.x;
  int xcd = bid & 7, r0 = bid >> 3;          // r0 in [0,96)
  int fam3 = r0 % 3;
  bool isV = (fam3 == 2);
  int m0, n0;
  const u16 *arows, *brows;
  if (!isV) {
    int qi = (r0 / 3) * 2 + fam3;            // [0,64)
    m0 = (qi >> 1) * 128;
    n0 = (xcd * 2 + (qi & 1)) * 128;
    arows = A + (size_t)m0 * K_DIM;
    brows = Bt + (size_t)n0 * K_DIM;
  } else {
    m0 = xcd * 128;                          // vrow panel
    n0 = (r0 / 3) * 128;                     // s panel
    arows = Bt + (size_t)(2048 + m0) * K_DIM;
    brows = A + (size_t)n0 * K_DIM;
  }
  float qscale = (!isV && (n0 + wc) < 1024) ? 0.18033688f : 1.0f;  // 0.125*log2e
  f32x4 acc[4][4];
#pragma unroll
  for (int m = 0; m < 4; m++)
#pragma unroll
    for (int n = 0; n < 4; n++)
#pragma unroll
      for (int j = 0; j < 4; j++) acc[m][n][j] = 0.f;

  // hoisted: per-thread staging sources (advance += 32 u16 per K-step)
  const u16 *asrc[2], *bsrc[2];
#pragma unroll
  for (int i = 0; i < 2; ++i) {
    int ci = i * 256 + t;                    // linear 16B-chunk index
    int rowp = ci >> 3, cp = ci & 7;
    int cc = cp ^ (rowp & 7);
    int r = 2 * rowp + (cc >> 2);
    int kchunk = cc & 3;
    asrc[i] = arows + (size_t)r * K_DIM + kchunk * 8;
    bsrc[i] = brows + (size_t)r * K_DIM + kchunk * 8;
  }
  // hoisted: MFMA LDS read offsets (lane-invariant across the K-loop)
  int aoff[4], boff[4];
#pragma unroll
  for (int m = 0; m < 4; m++) {
    int r = wr + m * 16 + l15;
    int rowp = r >> 1;
    int cp = ((r & 1) * 4 + hi) ^ (rowp & 7);
    aoff[m] = rowp * 64 + cp * 8;
  }
#pragma unroll
  for (int n = 0; n < 4; n++) {
    int r = wc + n * 16 + l15;
    int rowp = r >> 1;
    int cp = ((r & 1) * 4 + hi) ^ (rowp & 7);
    boff[n] = rowp * 64 + cp * 8;
  }

  auto stage = [&](int buf) {
#pragma unroll
    for (int i = 0; i < 2; ++i) {
      gload_lds16(asrc[i], (char*)As[buf] + (size_t)(i * 256 + w * 64) * 16);
      gload_lds16(bsrc[i], (char*)Bs[buf] + (size_t)(i * 256 + w * 64) * 16);
      asrc[i] += 32;
      bsrc[i] += 32;
    }
  };

  stage(0);
  __syncthreads();

  int cur = 0;
  for (int t32 = 0; t32 < 32; ++t32) {
    if (t32 < 31) stage(cur ^ 1);            // loads in flight during compute
    bf16x8 af[4], bfr[4];
#pragma unroll
    for (int m = 0; m < 4; m++) af[m] = *(const bf16x8*)&As[cur][aoff[m]];
#pragma unroll
    for (int n = 0; n < 4; n++) bfr[n] = *(const bf16x8*)&Bs[cur][boff[n]];
    __builtin_amdgcn_s_setprio(1);
#pragma unroll
    for (int m = 0; m < 4; m++)
#pragma unroll
      for (int n = 0; n < 4; n++)
        acc[m][n] = __builtin_amdgcn_mfma_f32_16x16x32_bf16(af[m], bfr[n], acc[m][n], 0, 0, 0);
    __builtin_amdgcn_s_setprio(0);
    __syncthreads();   // drains next-tile DMA (covered by compute) + frees cur
    cur ^= 1;
  }

  if (!isV) {
#pragma unroll
    for (int m = 0; m < 4; m++) {
#pragma unroll
      for (int r = 0; r < 4; r++) {
        int row = m0 + wr + m * 16 + hi * 4 + r;
#pragma unroll
        for (int n = 0; n < 4; n++) {
          int col = n0 + wc + n * 16 + l15;
          Cqk[(size_t)row * QK_COLS + col] = f2b(acc[m][n][r] * qscale);
        }
      }
    }
  } else {
#pragma unroll
    for (int m = 0; m < 4; m++) {
#pragma unroll
      for (int r = 0; r < 4; r++) {
        int vrow = m0 + wr + m * 16 + hi * 4 + r;      // 0..1023 (h*64+e)
#pragma unroll
        for (int n = 0; n < 4; n++) {
          int col = n0 + wc + n * 16 + l15;            // s in [0,4096)
          VT[(size_t)((col >> 11) * 1024 + vrow) * S_LEN + (col & 2047)] =
              f2b(acc[m][n][r]);
        }
      }
    }
  }
}

// ---- attention helpers (256-thread block) ----
// K staging with sigma-permuted SOURCE rows: LDS row r holds kv0+sigma(r); the
// XOR chunk swizzle keys on the LDS row (read side unchanged).
__device__ __forceinline__ void stage_k(const u16* kb_, u16* kdst, int kv0, int t, int w) {
#pragma unroll
  for (int i = 0; i < 2; ++i) {
    int ci = i * 256 + t;
    int row = ci >> 3, c = ci & 7;
    int srow = sigma64(row);
    int cs = c ^ (row & 7);
    gload_lds16(kb_ + (size_t)(kv0 + srow) * QK_COLS + cs * 8,
                (char*)kdst + (size_t)(i * 256 + w * 64) * 16);  // wave-uniform base
  }
}

// V^T stage: VT rows are e (stride S_LEN u16), tile cols [kv0, kv0+64) natural order.
__device__ __forceinline__ void stage_v(const u16* vtb_, u16* vdst, int kv0, int t, int w) {
#pragma unroll
  for (int i = 0; i < 2; ++i) {
    int ci = i * 256 + t;
    int row = ci >> 3, c = ci & 7;
    int cs = c ^ (row & 7);
    gload_lds16(vtb_ + (size_t)row * S_LEN + kv0 + cs * 8,
                (char*)vdst + (size_t)(i * 256 + w * 64) * 16);
  }
}

// ------- flash attention, causal, swapped-QK^T register-P, DMA-staged V^T -------
// 1024 blocks x 4 waves; x=bid&7, g=bid>>3, bh=x*4+(g&3) (4 heads' K/V per XCD L2),
// qt=31-(g>>2) (LPT). Wave owns 16 q rows. QK^T as mfma(K,Q) -> P register-local.
// Ks rows sigma-permuted at staging so PV's A k-map (kv=32ks+8hi+j) aligns with
// NATURAL V^T columns: V fragment = ONE b128, A/B k-maps agree exactly.
// Diagonal mask uses kv = kv0 + sigma(16f+4hi+r). No-max exp2 softmax.
__global__ __launch_bounds__(256) void k_attn(const u16* __restrict__ qk,
                                              const u16* __restrict__ VT,
                                              float* __restrict__ out) {
  __shared__ __align__(16) u16 Ks[2][64 * 64];
  __shared__ __align__(16) u16 Vs[2][64 * 64];
  int t = threadIdx.x;
  int lane = t & 63, w = t >> 6;
  int hi = lane >> 4, l15 = lane & 15;
  int bid = blockIdx.x;                 // 0..1023
  int x = bid & 7, g = bid >> 3;
  int bh = x * 4 + (g & 3);
  int qt = 31 - (g >> 2);
  int b = bh >> 4, h = bh & 15;
  const u16* qb_ = qk + (size_t)b * S_LEN * QK_COLS + h * NE;
  const u16* kb_ = qb_ + 1024;
  const u16* vtb_ = VT + (size_t)bh * 64 * S_LEN;

  int q0 = qt * 64;
  int nt = qt + 1;
  int wqb = q0 + w * 16;                // wave q base; lane q = wqb + l15

  bf16x8 qf[2];
#pragma unroll
  for (int ks = 0; ks < 2; ks++)
    qf[ks] = *(const bf16x8*)(qb_ + (size_t)(wqb + l15) * QK_COLS + ks * 32 + hi * 8);

  f32x4 o[4];
#pragma unroll
  for (int i = 0; i < 4; i++)
#pragma unroll
    for (int j = 0; j < 4; j++) o[i][j] = 0.f;
  float lsum = 0.f;
  int myq = wqb + l15;

  // prologue: stage tile 0 into buffer 0
  stage_k(kb_, Ks[0], 0, t, w);
  stage_v(vtb_, Vs[0], 0, t, w);
  __syncthreads();

  int cur = 0;
  for (int ti = 0; ti < nt; ++ti) {
    int kv0 = ti * 64;
    bool pf = (ti + 1 < nt);
    if (pf) {
      stage_k(kb_, Ks[cur ^ 1], kv0 + 64, t, w);
      stage_v(vtb_, Vs[cur ^ 1], kv0 + 64, t, w);
    }

    // S^T = K Q : s[f][r] = S[kv = kv0 + sigma(16f+4hi+r)][q = myq]
    f32x4 s[4];
#pragma unroll
    for (int f = 0; f < 4; f++)
#pragma unroll
      for (int j = 0; j < 4; j++) s[f][j] = 0.f;
    __builtin_amdgcn_s_setprio(1);
#pragma unroll
    for (int ks = 0; ks < 2; ks++) {
      int kc = ks * 4 + hi;
#pragma unroll
      for (int f = 0; f < 4; f++) {
        int r = f * 16 + l15;
        bf16x8 kf = *(const bf16x8*)&Ks[cur][r * 64 + ((kc ^ (r & 7)) * 8)];
        s[f] = __builtin_amdgcn_mfma_f32_16x16x32_bf16(kf, qf[ks], s[f], 0, 0, 0);
      }
    }
    __builtin_amdgcn_s_setprio(0);

    // no-max softmax: p = exp2(s); diagonal mask with sigma-mapped kv
    bool diag = (ti == nt - 1);
#pragma unroll
    for (int f = 0; f < 4; f++) {
#pragma unroll
      for (int r = 0; r < 4; r++) {
        float p = __builtin_amdgcn_exp2f(s[f][r]);
        if (diag) {
          int kv = kv0 + sigma64(16 * f + 4 * hi + r);
          p = (kv <= myq) ? p : 0.f;
        }
        s[f][r] = p;
        lsum += p;
      }
    }

    // PV: pa register-local (pa slot (hi,j) holds kv = 32ks+8hi+j after sigma);
    // V fragment = ONE b128 from Vs natural layout, chunk (4ks+hi)^(e&7).
    __builtin_amdgcn_s_setprio(1);
#pragma unroll
    for (int ks = 0; ks < 2; ks++) {
      bf16x8 pa;
#pragma unroll
      for (int j = 0; j < 4; j++) {
        pa[j] = (__bf16)s[2 * ks][j];
        pa[4 + j] = (__bf16)s[2 * ks + 1][j];
      }
#pragma unroll
      for (int ef = 0; ef < 4; ef++) {
        int e = ef * 16 + l15;
        bf16x8 vbf = *(const bf16x8*)&Vs[cur][e * 64 + (((4 * ks + hi) ^ (e & 7)) * 8)];
        o[ef] = __builtin_amdgcn_mfma_f32_16x16x32_bf16(pa, vbf, o[ef], 0, 0, 0);
      }
    }
    __builtin_amdgcn_s_setprio(0);
    __syncthreads();
    cur ^= 1;
  }

  // epilogue: complete row-sum across hi groups, redistribute, normalize, store.
  lsum += __shfl_xor(lsum, 16);
  lsum += __shfl_xor(lsum, 32);
#pragma unroll
  for (int r = 0; r < 4; r++) {
    float l = __shfl(lsum, 4 * hi + r);  // lane 4hi+r holds sum for q = wqb+4hi+r
    float inv = 1.0f / l;
    int q = wqb + 4 * hi + r;
#pragma unroll
    for (int ef = 0; ef < 4; ef++) {
      int col = h * NE + ef * 16 + l15;
      out[((size_t)b * S_LEN + q) * (NH * NE) + col] = o[ef][r] * inv;
    }
  }
}

extern "C" void kernel_launch(void* const* d_in, const int* in_sizes, int n_in,
                              void* d_out, int out_size, void* d_ws, size_t ws_size,
                              hipStream_t stream) {
  const float* x = (const float*)d_in[0];
  const float* Wq = (const float*)d_in[1];
  const float* Wk = (const float*)d_in[2];
  const float* Wv = (const float*)d_in[3];
  float* out = (float*)d_out;

  char* ws = (char*)d_ws;
  u16* xb = (u16*)ws;                          // 4096*1024*2  = 8 MB
  u16* Wt = (u16*)(ws + (8u << 20));           // 3072*1024*2  = 6 MB
  u16* qk = (u16*)(ws + (14u << 20));          // 4096*2048*2  = 16 MB
  u16* VT = (u16*)(ws + (30u << 20));          // 32*64*2048*2 = 8 MB

  k_prep<<<dim3(2816), dim3(256), 0, stream>>>(x, Wq, Wk, Wv, xb, Wt);
  k_gemm<<<dim3(768), dim3(256), 0, stream>>>(xb, Wt, qk, VT);
  k_attn<<<dim3(1024), dim3(256), 0, stream>>>(qk, VT, out);
}